// Round 17
// baseline (658.809 us; speedup 1.0000x reference)
//
#include <hip/hip_runtime.h>

#define B_  8
#define C_  128
#define H_  128
#define W_  256
#define HW_ (H_ * W_)
#define TH  8
#define TW  32
#define F2RS 72                    // f2 row stride (dw)
#define F2PT (16 * F2RS)           // 1152 dw per f2 pair-tile (16 rows)
#define F1RS 40                    // f1 row stride (dw): 2-way banks (free)
#define F1PT (8 * F1RS)            // 320 dw per f1 pair-tile
#define F1OFF (2 * F2PT)           // 2304
#define BUFN (F1OFF + 2 * F1PT)    // 2944 dw per buffer (11.8 KB; dbuf 23.6 KB)
#define NTHREADS 512

typedef __fp16 h2 __attribute__((ext_vector_type(2)));

__device__ __forceinline__ float dot2f16(unsigned int a, unsigned int b, float c) {
#if __has_builtin(__builtin_amdgcn_fdot2)
    return __builtin_amdgcn_fdot2(__builtin_bit_cast(h2, a),
                                  __builtin_bit_cast(h2, b), c, false);
#else
    h2 ha = __builtin_bit_cast(h2, a), hb = __builtin_bit_cast(h2, b);
    return c + (float)ha.x * (float)hb.x + (float)ha.y * (float)hb.y;
#endif
}

__device__ __forceinline__ unsigned int pk(float x, float y) {
    h2 r = __builtin_amdgcn_cvt_pkrtz(x, y);
    return __builtin_bit_cast(unsigned int, r);
}

// 8-wave block (512 thr), wave = di 0..7 with r9's acc[9dj][4px]=36.
// di=8 split BY DJ across waves: wave w computes plane (8, dj=w) only
// (wave 7 also dj=8) -> acc8[2][4]=8 regs + one targeted 2xb128 read of
// f2 row hh+8. NPAIR=2 (4ch/stage, 32 stages) -> staged = 2 float4.
// Single-slot staging (448 stagers). Live ~94 regs < 128 cap of
// bounds(512,4) -> TWO blocks/CU (r16-proven occupancy) without r16's spill.
// Depth-1.5 pipeline, raw s_barrier + lgkmcnt(0) (counted vmcnt on loads).
__global__ __launch_bounds__(NTHREADS, 4) void cv_kernel(
    const float* __restrict__ f1g, const float* __restrict__ f2g,
    float* __restrict__ outg) {
    __shared__ __align__(16) unsigned int lds[2][BUFN];

    const int tid = threadIdx.x;
    const int w0 = blockIdx.x * TW;
    const int h0 = blockIdx.y * TH;
    const int b  = blockIdx.z;

    // ---- staging (single slot): tid<320 f2 (2pp x 16r x 10u); 320..447 f1 ----
    const bool stg = (tid < 448);
    int offS = 0, ldS = 0;
    float mS = 0.f;
    const float* pS = f1g;
    if (tid < 320) {
        int pp = tid / 160, rem = tid % 160;
        int r = rem / 10, u = rem % 10;
        int gh = h0 - 4 + r, gw = w0 - 4 + 4 * u;
        bool valid = (gh >= 0) && (gh < H_) && (gw >= 0) && (gw <= W_ - 4);
        int ghc = min(max(gh, 0), H_ - 1);
        int gwc = min(max(gw, 0), W_ - 4);
        offS = ((b * C_ + 2 * pp) * H_ + ghc) * W_ + gwc;
        pS   = f2g;
        ldS  = pp * F2PT + r * F2RS + 4 * u;
        mS   = valid ? 1.f : 0.f;
    } else if (tid < 448) {
        int t = tid - 320;             // 0..127: 2pp x 8r x 8u
        int pp = t >> 6, r = (t >> 3) & 7, u = t & 7;
        offS = ((b * C_ + 2 * pp) * H_ + h0 + r) * W_ + w0 + 4 * u;
        pS   = f1g;
        ldS  = F1OFF + pp * F1PT + r * F1RS + 4 * u;
        mS   = 1.f;
    }

#define LOADST(Sa, Sb)                                                        \
    do { if (stg) {                                                           \
        Sa = *(const float4*)(pS + offS);                                     \
        Sb = *(const float4*)(pS + offS + HW_);                               \
        offS += 4 * HW_;                                                      \
    } } while (0)

#define STOREST(bi, Sa, Sb)                                                   \
    do { if (stg) {                                                           \
        uint4 wv;                                                             \
        wv.x = pk(Sa.x * mS, Sb.x * mS);                                      \
        wv.y = pk(Sa.y * mS, Sb.y * mS);                                      \
        wv.z = pk(Sa.z * mS, Sb.z * mS);                                      \
        wv.w = pk(Sa.w * mS, Sb.w * mS);                                      \
        *(uint4*)(&lds[bi][ldS]) = wv;                                        \
    } } while (0)

#define BAR()                                                                 \
    do {                                                                      \
        asm volatile("s_waitcnt lgkmcnt(0)" ::: "memory");                    \
        __builtin_amdgcn_s_barrier();                                         \
    } while (0)

    // ---- compute mapping ----
    const int di   = tid >> 6;       // 0..7 (primary di; also secondary dj)
    const int lane = tid & 63;
    const int hh   = lane >> 3;      // 0..7
    const int sc   = lane & 7;       // 0..7, 4-px strip
    const int wo   = di >> 2;        // secondary read window offset (0/1)
    const int dlo  = di & 3;         // secondary index low bits
    const int rd0  = (hh + di) * F2RS + 4 * sc;          // primary f2 row
    const int rd8  = (hh + 8) * F2RS + 4 * (sc + wo);    // di=8 f2 row window
    const int rf0  = F1OFF + hh * F1RS + 4 * sc;         // f1 unit sc
    const bool w7  = (di == 7);

    float acc[9][4];
#pragma unroll
    for (int j = 0; j < 9; ++j)
#pragma unroll
        for (int p = 0; p < 4; ++p) acc[j][p] = 0.f;
    float acc8[2][4];
#pragma unroll
    for (int t = 0; t < 2; ++t)
#pragma unroll
        for (int p = 0; p < 4; ++p) acc8[t][p] = 0.f;

#define COMPUTE(bi)                                                           \
    do {                                                                      \
        _Pragma("unroll")                                                     \
        for (int q = 0; q < 2; ++q) {                                         \
            const unsigned int* bf2 = &lds[bi][q * F2PT];                     \
            const unsigned int* bf1 = &lds[bi][q * F1PT];                     \
            uint4 ga = *(const uint4*)(bf1 + rf0);                            \
            unsigned int f1u[4] = {ga.x, ga.y, ga.z, ga.w};                   \
            uint4 fa = *(const uint4*)(bf2 + rd0);                            \
            uint4 fb = *(const uint4*)(bf2 + rd0 + 4);                        \
            uint4 fc = *(const uint4*)(bf2 + rd0 + 8);                        \
            unsigned int f2u[12] = {fa.x, fa.y, fa.z, fa.w,                   \
                                    fb.x, fb.y, fb.z, fb.w,                   \
                                    fc.x, fc.y, fc.z, fc.w};                  \
            _Pragma("unroll")                                                 \
            for (int j = 0; j < 9; ++j)                                       \
                _Pragma("unroll")                                             \
                for (int p = 0; p < 4; ++p)                                   \
                    acc[j][p] = dot2f16(f1u[p], f2u[p + j], acc[j][p]);       \
            uint4 s0 = *(const uint4*)(bf2 + rd8);                            \
            uint4 s1 = *(const uint4*)(bf2 + rd8 + 4);                        \
            unsigned int u8v[8] = {s0.x, s0.y, s0.z, s0.w,                    \
                                   s1.x, s1.y, s1.z, s1.w};                   \
            _Pragma("unroll")                                                 \
            for (int p = 0; p < 4; ++p)                                       \
                acc8[0][p] = dot2f16(f1u[p], u8v[dlo + p], acc8[0][p]);       \
            if (w7) {                                                         \
                _Pragma("unroll")                                             \
                for (int p = 0; p < 4; ++p)                                   \
                    acc8[1][p] = dot2f16(f1u[p], u8v[4 + p], acc8[1][p]);     \
            }                                                                 \
        }                                                                     \
    } while (0)

    float4 aA, bA, aB, bB;

    // prologue: stage 0 -> buf0
    LOADST(aA, bA);
    STOREST(0, aA, bA);
    BAR();

    // 32 stages of 4 channels, depth-1.5
    for (int st = 0; st < 30; st += 2) {
        LOADST(aB, bB);              // stage st+1 (in flight over compute)
        COMPUTE(0);                  // stage st
        STOREST(1, aB, bB);          // stage st+1 (counted vmcnt)
        BAR();
        LOADST(aA, bA);              // stage st+2
        COMPUTE(1);                  // stage st+1
        STOREST(0, aA, bA);          // stage st+2
        BAR();
    }
    LOADST(aB, bB);                  // stage 31
    COMPUTE(0);                      // stage 30
    STOREST(1, aB, bB);              // stage 31
    BAR();
    COMPUTE(1);                      // stage 31

    // ---- epilogue ----
    const float inv = 1.0f / 128.0f;
    int obase = ((b * 81 + di * 9) * H_ + h0 + hh) * W_ + w0 + 4 * sc;
#pragma unroll
    for (int j = 0; j < 9; ++j) {
        float4 o = make_float4(acc[j][0] * inv, acc[j][1] * inv,
                               acc[j][2] * inv, acc[j][3] * inv);
        *(float4*)(outg + obase) = o;
        obase += HW_;
    }
    // secondary: plane (di=8, dj=di); wave 7 also dj=8
    {
        int o8 = ((b * 81 + 72 + di) * H_ + h0 + hh) * W_ + w0 + 4 * sc;
        float4 o = make_float4(acc8[0][0] * inv, acc8[0][1] * inv,
                               acc8[0][2] * inv, acc8[0][3] * inv);
        *(float4*)(outg + o8) = o;
        if (w7) {
            int o9 = ((b * 81 + 80) * H_ + h0 + hh) * W_ + w0 + 4 * sc;
            float4 o2 = make_float4(acc8[1][0] * inv, acc8[1][1] * inv,
                                    acc8[1][2] * inv, acc8[1][3] * inv);
            *(float4*)(outg + o9) = o2;
        }
    }
}

extern "C" void kernel_launch(void* const* d_in, const int* in_sizes, int n_in,
                              void* d_out, int out_size, void* d_ws, size_t ws_size,
                              hipStream_t stream) {
    const float* f1 = (const float*)d_in[0];
    const float* f2 = (const float*)d_in[1];
    float* out = (float*)d_out;
    dim3 grid(W_ / TW, H_ / TH, B_);   // 8 x 16 x 8 = 1024 blocks
    cv_kernel<<<grid, NTHREADS, 0, stream>>>(f1, f2, out);
}